// Round 6
// baseline (226.128 us; speedup 1.0000x reference)
//
#include <hip/hip_runtime.h>

#define SEQ 2048
#define DMODEL 1024
#define HEADS 16
#define DH 64
// fold (1/sqrt(64)) * log2(e) into Wq so scores arrive in exp2 domain
#define QSCALE 0.180336880f

typedef __attribute__((ext_vector_type(8))) short short8;
typedef __attribute__((ext_vector_type(4))) float f32x4;

__device__ __forceinline__ ushort f2bf(float x) {
  union { float f; unsigned u; } v; v.f = x;
  return (ushort)((v.u + 0x7fffu + ((v.u >> 16) & 1u)) >> 16);
}

// async global->LDS, 16B per lane. LDS dest = wave-uniform base + lane*16.
__device__ __forceinline__ void gld16(const ushort* g, ushort* l) {
  __builtin_amdgcn_global_load_lds(
      (const __attribute__((address_space(1))) unsigned int*)g,
      (__attribute__((address_space(3))) unsigned int*)l, 16, 0, 0);
}

// fragment-major index for Q/K [bh][s>>4][d>>5][lane q*16+ln][j=d&7]
__device__ __forceinline__ size_t qk_idx(int bh, int s, int d) {
  return ((((size_t)bh * (SEQ / 16) + (s >> 4)) * 2 + (d >> 5)) * 64 +
          ((d >> 3) & 3) * 16 + (s & 15)) * 8 + (d & 7);
}
// fragment-major index for V^T [bh][d>>4][s>>5][lane][j=s&7]
__device__ __forceinline__ size_t v_idx(int bh, int s, int d) {
  return ((((size_t)bh * 4 + (d >> 4)) * (SEQ / 32) + (s >> 5)) * 64 +
          ((s >> 3) & 3) * 16 + (d & 15)) * 8 + (s & 7);
}

// ---------------------------------------------------------------------------
// Fused prologue. z=0/1: fp32->bf16 cast of patch/pixel (4x float4/thread).
// z=2..5: transpose-cast Wq*QSCALE / Wk / Wv / Wo to [N][K] bf16.
// grid (32,32,6), block (32,8).
// ---------------------------------------------------------------------------
__global__ __launch_bounds__(256) void prologue(
    const float* __restrict__ patch, const float* __restrict__ pixel,
    const float* __restrict__ W0, const float* __restrict__ W1,
    const float* __restrict__ W2, const float* __restrict__ W3,
    ushort* __restrict__ pb, ushort* __restrict__ xb,
    ushort* __restrict__ O0, ushort* __restrict__ O1,
    ushort* __restrict__ O2, ushort* __restrict__ O3) {
  const int z = blockIdx.z;
  const int tx = threadIdx.x, ty = threadIdx.y;
  if (z < 2) {
    const float4* in = (const float4*)(z ? pixel : patch);
    ushort4* out = (ushort4*)(z ? xb : pb);
    const int base = (blockIdx.y * 32 + blockIdx.x) * 256 + ty * 32 + tx;
#pragma unroll
    for (int rep = 0; rep < 4; ++rep) {
      const int i = base + rep * 262144;
      float4 f = in[i];
      out[i] = make_ushort4(f2bf(f.x), f2bf(f.y), f2bf(f.z), f2bf(f.w));
    }
    return;
  }
  __shared__ float tile[32][33];
  const int zz = z - 2;
  const float* in = zz == 0 ? W0 : zz == 1 ? W1 : zz == 2 ? W2 : W3;
  ushort* out = zz == 0 ? O0 : zz == 1 ? O1 : zz == 2 ? O2 : O3;
  const float scale = zz == 0 ? QSCALE : 1.0f;
  const int n0 = blockIdx.x * 32, k0 = blockIdx.y * 32;
#pragma unroll
  for (int i = 0; i < 4; ++i)
    tile[ty + i * 8][tx] = in[(size_t)(k0 + ty + i * 8) * DMODEL + n0 + tx];
  __syncthreads();
#pragma unroll
  for (int i = 0; i < 4; ++i)
    out[(size_t)(n0 + ty + i * 8) * DMODEL + k0 + tx] =
        f2bf(tile[tx][ty + i * 8] * scale);
}

// ---------------------------------------------------------------------------
// Fused Q/K/V projection GEMM, global_load_lds(16B) staging, XOR-swizzled on
// the GLOBAL side. 128x128 tile, BK=64, 4 waves. Epilogues scatter to the
// fragment-major layouts consumed by flash_mfma.
// ---------------------------------------------------------------------------
__global__ __launch_bounds__(256) void mfma_gemm_qkv(
    const ushort* __restrict__ pb, const ushort* __restrict__ xb,
    const ushort* __restrict__ wqt, const ushort* __restrict__ wkt,
    const ushort* __restrict__ wvt, ushort* __restrict__ qws,
    ushort* __restrict__ kws, ushort* __restrict__ vws) {
  __shared__ __align__(16) ushort As[128 * 64];
  __shared__ __align__(16) ushort Bs[128 * 64];
  const int z = blockIdx.z;
  const ushort* A = (z == 0) ? pb : xb;
  const ushort* Bt = (z == 0) ? wqt : (z == 1) ? wkt : wvt;

  const int t = threadIdx.x;
  const int w = t >> 6, lane = t & 63, ln = lane & 15, q = lane >> 4;
  const int wm = w & 1, wn = w >> 1;
  const int row0 = blockIdx.y * 128, col0 = blockIdx.x * 128;
  const int sw = ln & 7;

  f32x4 acc[4][4];
#pragma unroll
  for (int i = 0; i < 4; ++i)
#pragma unroll
    for (int j = 0; j < 4; ++j) acc[i][j] = (f32x4){0.f, 0.f, 0.f, 0.f};

  for (int k0 = 0; k0 < DMODEL; k0 += 64) {
    __syncthreads();  // prior frag reads done
#pragma unroll
    for (int rep = 0; rep < 4; ++rep) {
      const int u0 = rep * 256 + w * 64;
      const int u = u0 + lane;
      const int r = u >> 3, gl = (u & 7) ^ (r & 7);
      gld16(&A[(size_t)(row0 + r) * DMODEL + k0 + gl * 8], &As[u0 * 8]);
      gld16(&Bt[(size_t)(col0 + r) * DMODEL + k0 + gl * 8], &Bs[u0 * 8]);
    }
    __syncthreads();  // vmcnt drain
#pragma unroll
    for (int ks = 0; ks < 2; ++ks) {
      short8 af[4], bf[4];
#pragma unroll
      for (int rt = 0; rt < 4; ++rt)
        af[rt] = *(const short8*)&As[(wm * 64 + rt * 16 + ln) * 64 +
                                     (((ks * 4 + q) ^ sw) * 8)];
#pragma unroll
      for (int ct = 0; ct < 4; ++ct)
        bf[ct] = *(const short8*)&Bs[(wn * 64 + ct * 16 + ln) * 64 +
                                     (((ks * 4 + q) ^ sw) * 8)];
#pragma unroll
      for (int rt = 0; rt < 4; ++rt)
#pragma unroll
        for (int ct = 0; ct < 4; ++ct)
          acc[rt][ct] = __builtin_amdgcn_mfma_f32_16x16x32_bf16(af[rt], bf[ct],
                                                                acc[rt][ct], 0, 0, 0);
    }
  }

  if (z < 2) {
    ushort* dst = z == 0 ? qws : kws;
#pragma unroll
    for (int rt = 0; rt < 4; ++rt)
#pragma unroll
      for (int ct = 0; ct < 4; ++ct) {
        const int c = col0 + wn * 64 + ct * 16 + ln;
        const int h = c >> 6, d = c & 63;
#pragma unroll
        for (int reg = 0; reg < 4; ++reg) {
          const int r = row0 + wm * 64 + rt * 16 + q * 4 + reg;
          const int b = r >> 11, s = r & (SEQ - 1);
          dst[qk_idx(b * HEADS + h, s, d)] = f2bf(acc[rt][ct][reg]);
        }
      }
  } else {
#pragma unroll
    for (int rt = 0; rt < 4; ++rt)
#pragma unroll
      for (int ct = 0; ct < 4; ++ct) {
        const int c = col0 + wn * 64 + ct * 16 + ln;
        const int h = c >> 6, d = c & 63;
        const int r0 = row0 + wm * 64 + rt * 16 + q * 4;
        const int b = r0 >> 11, s0 = r0 & (SEQ - 1);
        ushort4 u4 = make_ushort4(f2bf(acc[rt][ct][0]), f2bf(acc[rt][ct][1]),
                                  f2bf(acc[rt][ct][2]), f2bf(acc[rt][ct][3]));
        *(ushort4*)&vws[v_idx(b * HEADS + h, s0, d)] = u4;
      }
  }
}

// ---------------------------------------------------------------------------
// Flash attention, K-split x2 into DISJOINT partial buffers (additive merge:
// max-free exp2 softmax => O/l partials sum exactly). No atomics, no memset,
// zero in-loop barriers. Wave = 16 Q rows x 16-iter K sweep.
// Grid (32 qt, 32 bh, 2 seg) = 2048 blocks = 8 blocks/CU = 32 waves/CU.
// ---------------------------------------------------------------------------
__global__ __launch_bounds__(256) void flash_mfma(
    const ushort* __restrict__ Qg, const ushort* __restrict__ Kg,
    const ushort* __restrict__ Vg, float* __restrict__ PO0,
    float* __restrict__ PO1, float* __restrict__ L0, float* __restrict__ L1) {
  __shared__ __align__(16) ushort Ps[64 * 72];

  const int t = threadIdx.x;
  const int w = t >> 6, lane = t & 63, ln = lane & 15, q = lane >> 4;
  const int qt = blockIdx.x;   // 0..31 (64-row Q tile)
  const int bh = blockIdx.y;   // 0..31
  const int seg = blockIdx.z;  // 0..1

  float* __restrict__ PO = seg ? PO1 : PO0;
  float* __restrict__ Lb = seg ? L1 : L0;

  const ushort* qg = Qg + (size_t)bh * SEQ * DH;
  const ushort* kg = Kg + (size_t)bh * SEQ * DH;
  const ushort* vg = Vg + (size_t)bh * DH * SEQ;

  // Q A-fragments, coalesced
  short8 qf[2];
#pragma unroll
  for (int ks = 0; ks < 2; ++ks)
    qf[ks] = *(const short8*)&qg[((((size_t)(qt * 4 + w)) * 2 + ks) * 64 + lane) * 8];

  float l_i[4] = {0.f, 0.f, 0.f, 0.f};
  f32x4 acc_o[4];
#pragma unroll
  for (int nt = 0; nt < 4; ++nt) acc_o[nt] = (f32x4){0.f, 0.f, 0.f, 0.f};

  for (int kt = seg * 16; kt < seg * 16 + 16; ++kt) {
    // V^T frags first (independent -> long load->use distance)
    short8 bv[2][4];
#pragma unroll
    for (int ks2 = 0; ks2 < 2; ++ks2)
#pragma unroll
      for (int nt = 0; nt < 4; ++nt)
        bv[ks2][nt] = *(const short8*)&vg[(((size_t)nt * (SEQ / 32) + kt * 2 + ks2) *
                                           64 + lane) * 8];

    // S = Q @ K^T (wave: 16 x 64); K frags coalesced
    f32x4 accs[4];
#pragma unroll
    for (int ct = 0; ct < 4; ++ct) accs[ct] = (f32x4){0.f, 0.f, 0.f, 0.f};
#pragma unroll
    for (int ks = 0; ks < 2; ++ks) {
      short8 bfr[4];
#pragma unroll
      for (int ct = 0; ct < 4; ++ct)
        bfr[ct] = *(const short8*)&kg[((((size_t)(kt * 4 + ct)) * 2 + ks) * 64 +
                                       lane) * 8];
#pragma unroll
      for (int ct = 0; ct < 4; ++ct)
        accs[ct] = __builtin_amdgcn_mfma_f32_16x16x32_bf16(qf[ks], bfr[ct],
                                                           accs[ct], 0, 0, 0);
    }

    // p = 2^s (Q pre-scaled), lane-partial l, P -> wave-private LDS rows
#pragma unroll
    for (int ct = 0; ct < 4; ++ct)
#pragma unroll
      for (int reg = 0; reg < 4; ++reg) {
        const float p = __builtin_amdgcn_exp2f(accs[ct][reg]);
        l_i[reg] += p;
        Ps[(w * 16 + q * 4 + reg) * 72 + ct * 16 + ln] = f2bf(p);
      }

    // O += P @ V
#pragma unroll
    for (int ks2 = 0; ks2 < 2; ++ks2) {
      const short8 pa = *(const short8*)&Ps[(w * 16 + ln) * 72 + ks2 * 32 + q * 8];
#pragma unroll
      for (int nt = 0; nt < 4; ++nt)
        acc_o[nt] = __builtin_amdgcn_mfma_f32_16x16x32_bf16(pa, bv[ks2][nt],
                                                            acc_o[nt], 0, 0, 0);
    }
  }

  // epilogue: write RAW partials (no normalize) to this segment's buffers
#pragma unroll
  for (int reg = 0; reg < 4; ++reg) {
    float l = l_i[reg];
    l += __shfl_xor(l, 1, 16);
    l += __shfl_xor(l, 2, 16);
    l += __shfl_xor(l, 4, 16);
    l += __shfl_xor(l, 8, 16);
    const int s = qt * 64 + w * 16 + q * 4 + reg;
    if (ln == 0) Lb[bh * SEQ + s] = l;
#pragma unroll
    for (int nt = 0; nt < 4; ++nt)
      PO[((size_t)bh * SEQ + s) * DH + nt * 16 + ln] = acc_o[nt][reg];
  }
}

// ---------------------------------------------------------------------------
// merge partials: aws = bf16( (PO0+PO1) / (L0+L1) ), layout [b*2048+s][h*64+d]
// ---------------------------------------------------------------------------
__global__ __launch_bounds__(256) void merge_reduce(
    const float4* __restrict__ PO0, const float4* __restrict__ PO1,
    const float* __restrict__ L0, const float* __restrict__ L1,
    ushort* __restrict__ aws) {
  const int i = blockIdx.x * 256 + threadIdx.x;  // float4 units, 0..1M-1
  const int row = i >> 4, d4 = i & 15;
  const int bh = row >> 11, s = row & (SEQ - 1);
  const int b = bh >> 4, h = bh & 15;
  const float4 a = PO0[i];
  const float4 c = PO1[i];
  const float inv = 1.0f / (L0[row] + L1[row]);
  ushort4 u = make_ushort4(f2bf((a.x + c.x) * inv), f2bf((a.y + c.y) * inv),
                           f2bf((a.z + c.z) * inv), f2bf((a.w + c.w) * inv));
  *(ushort4*)&aws[((size_t)b * SEQ + s) * DMODEL + h * DH + d4 * 4] = u;
}

// ---------------------------------------------------------------------------
// Output projection: out = aws[4096,1024] @ WoT^T + bo (fp32). 64x128 tile,
// BK=64, global_load_lds staging, 512 blocks.
// ---------------------------------------------------------------------------
__global__ __launch_bounds__(256) void mfma_gemm_out(const ushort* __restrict__ A,
                                                     const ushort* __restrict__ Bt,
                                                     const float* __restrict__ bias,
                                                     float* __restrict__ dst) {
  __shared__ __align__(16) ushort As[64 * 64];
  __shared__ __align__(16) ushort Bs[128 * 64];
  const int t = threadIdx.x;
  const int w = t >> 6, lane = t & 63, ln = lane & 15, q = lane >> 4;
  const int wm = w & 1, wn = w >> 1;
  const int row0 = blockIdx.y * 64, col0 = blockIdx.x * 128;
  const int sw = ln & 7;

  f32x4 acc[2][4];
#pragma unroll
  for (int i = 0; i < 2; ++i)
#pragma unroll
    for (int j = 0; j < 4; ++j) acc[i][j] = (f32x4){0.f, 0.f, 0.f, 0.f};

  for (int k0 = 0; k0 < DMODEL; k0 += 64) {
    __syncthreads();
#pragma unroll
    for (int rep = 0; rep < 2; ++rep) {
      const int u0 = rep * 256 + w * 64;
      const int u = u0 + lane;
      const int r = u >> 3, gl = (u & 7) ^ (r & 7);
      gld16(&A[(size_t)(row0 + r) * DMODEL + k0 + gl * 8], &As[u0 * 8]);
    }
#pragma unroll
    for (int rep = 0; rep < 4; ++rep) {
      const int u0 = rep * 256 + w * 64;
      const int u = u0 + lane;
      const int r = u >> 3, gl = (u & 7) ^ (r & 7);
      gld16(&Bt[(size_t)(col0 + r) * DMODEL + k0 + gl * 8], &Bs[u0 * 8]);
    }
    __syncthreads();
#pragma unroll
    for (int ks = 0; ks < 2; ++ks) {
      short8 af[2], bf[4];
#pragma unroll
      for (int rt = 0; rt < 2; ++rt)
        af[rt] = *(const short8*)&As[(wm * 32 + rt * 16 + ln) * 64 +
                                     (((ks * 4 + q) ^ sw) * 8)];
#pragma unroll
      for (int ct = 0; ct < 4; ++ct)
        bf[ct] = *(const short8*)&Bs[(wn * 64 + ct * 16 + ln) * 64 +
                                     (((ks * 4 + q) ^ sw) * 8)];
#pragma unroll
      for (int rt = 0; rt < 2; ++rt)
#pragma unroll
        for (int ct = 0; ct < 4; ++ct)
          acc[rt][ct] = __builtin_amdgcn_mfma_f32_16x16x32_bf16(af[rt], bf[ct],
                                                                acc[rt][ct], 0, 0, 0);
    }
  }

#pragma unroll
  for (int rt = 0; rt < 2; ++rt)
#pragma unroll
    for (int ct = 0; ct < 4; ++ct) {
      const int c = col0 + wn * 64 + ct * 16 + ln;
      const float bi = bias[c];
#pragma unroll
      for (int reg = 0; reg < 4; ++reg) {
        const int r = row0 + wm * 32 + rt * 16 + q * 4 + reg;
        dst[(size_t)r * DMODEL + c] = acc[rt][ct][reg] + bi;
      }
    }
}

extern "C" void kernel_launch(void* const* d_in, const int* in_sizes, int n_in,
                              void* d_out, int out_size, void* d_ws,
                              size_t ws_size, hipStream_t stream) {
  const float* patch = (const float*)d_in[0];
  const float* pixel = (const float*)d_in[1];
  const float* Wq = (const float*)d_in[2];
  const float* Wk = (const float*)d_in[3];
  const float* Wv = (const float*)d_in[4];
  const float* Wo = (const float*)d_in[5];
  const float* bo = (const float*)d_in[6];
  float* out = (float*)d_out;

  const size_t E = (size_t)2 * SEQ * DMODEL;  // 4,194,304
  const size_t W = (size_t)DMODEL * DMODEL;   // 1,048,576
  ushort* pb  = (ushort*)d_ws;      // patch bf16   (dead after qkv -> PO0)
  ushort* xb  = pb + E;             // pixel bf16   (part of PO0)
  ushort* wqt = xb + E;             // Wq^T*QSCALE  (dead after qkv -> L0/L1)
  ushort* wkt = wqt + W;
  ushort* wvt = wkt + W;
  ushort* wot = wvt + W;            // live until mfma_gemm_out
  ushort* qws = wot + W;            // Q fragment-major
  ushort* kws = qws + E;            // K fragment-major
  ushort* vws = kws + E;            // V^T fragment-major
  ushort* aws = vws + E;            // [4096][1024] row-major bf16

  // Partial buffers (no extra ws): PO0 overlays pb+xb (16 MB, dead after
  // qkv); PO1 = d_out itself (16 MB fp32, fully rewritten by final GEMM);
  // L0/L1 overlay wqt (dead after qkv).
  float* PO0 = (float*)pb;
  float* PO1 = out;
  float* L0 = (float*)wqt;
  float* L1 = L0 + 32 * SEQ;

  prologue<<<dim3(32, 32, 6), dim3(32, 8), 0, stream>>>(
      patch, pixel, Wq, Wk, Wv, Wo, pb, xb, wqt, wkt, wvt, wot);
  mfma_gemm_qkv<<<dim3(8, 32, 3), 256, 0, stream>>>(pb, xb, wqt, wkt, wvt,
                                                    qws, kws, vws);
  flash_mfma<<<dim3(32, 32, 2), 256, 0, stream>>>(qws, kws, vws, PO0, PO1, L0, L1);
  merge_reduce<<<dim3((32 * SEQ * DH / 4) / 256), 256, 0, stream>>>(
      (const float4*)PO0, (const float4*)PO1, L0, L1, aws);
  mfma_gemm_out<<<dim3(8, 64), 256, 0, stream>>>(aws, wot, bo, out);
}

// Round 7
// 207.789 us; speedup vs baseline: 1.0883x; 1.0883x over previous
//
#include <hip/hip_runtime.h>

#define SEQ 2048
#define DMODEL 1024
#define HEADS 16
#define DH 64
// fold (1/sqrt(64)) * log2(e) into Wq so scores arrive in exp2 domain
#define QSCALE 0.180336880f

typedef __attribute__((ext_vector_type(8))) short short8;
typedef __attribute__((ext_vector_type(4))) float f32x4;

__device__ __forceinline__ ushort f2bf(float x) {
  union { float f; unsigned u; } v; v.f = x;
  return (ushort)((v.u + 0x7fffu + ((v.u >> 16) & 1u)) >> 16);
}

// async global->LDS, 16B per lane. LDS dest = wave-uniform base + lane*16.
__device__ __forceinline__ void gld16(const ushort* g, ushort* l) {
  __builtin_amdgcn_global_load_lds(
      (const __attribute__((address_space(1))) unsigned int*)g,
      (__attribute__((address_space(3))) unsigned int*)l, 16, 0, 0);
}

// fragment-major index for Q/K [bh][s>>4][d>>5][lane q*16+ln][j=d&7]
__device__ __forceinline__ size_t qk_idx(int bh, int s, int d) {
  return ((((size_t)bh * (SEQ / 16) + (s >> 4)) * 2 + (d >> 5)) * 64 +
          ((d >> 3) & 3) * 16 + (s & 15)) * 8 + (d & 7);
}
// fragment-major index for V^T [bh][d>>4][s>>5][lane][j=s&7]
__device__ __forceinline__ size_t v_idx(int bh, int s, int d) {
  return ((((size_t)bh * 4 + (d >> 4)) * (SEQ / 32) + (s >> 5)) * 64 +
          ((s >> 3) & 3) * 16 + (d & 15)) * 8 + (s & 7);
}

// ---------------------------------------------------------------------------
// Fused prologue. z=0/1: fp32->bf16 cast of patch/pixel (4x float4/thread).
// z=2..5: transpose-cast Wq*QSCALE / Wk / Wv / Wo to [N][K] bf16.
// ---------------------------------------------------------------------------
__global__ __launch_bounds__(256) void prologue(
    const float* __restrict__ patch, const float* __restrict__ pixel,
    const float* __restrict__ W0, const float* __restrict__ W1,
    const float* __restrict__ W2, const float* __restrict__ W3,
    ushort* __restrict__ pb, ushort* __restrict__ xb,
    ushort* __restrict__ O0, ushort* __restrict__ O1,
    ushort* __restrict__ O2, ushort* __restrict__ O3) {
  const int z = blockIdx.z;
  const int tx = threadIdx.x, ty = threadIdx.y;
  if (z < 2) {
    const float4* in = (const float4*)(z ? pixel : patch);
    ushort4* out = (ushort4*)(z ? xb : pb);
    const int base = (blockIdx.y * 32 + blockIdx.x) * 256 + ty * 32 + tx;
#pragma unroll
    for (int rep = 0; rep < 4; ++rep) {
      const int i = base + rep * 262144;
      float4 f = in[i];
      out[i] = make_ushort4(f2bf(f.x), f2bf(f.y), f2bf(f.z), f2bf(f.w));
    }
    return;
  }
  __shared__ float tile[32][33];
  const int zz = z - 2;
  const float* in = zz == 0 ? W0 : zz == 1 ? W1 : zz == 2 ? W2 : W3;
  ushort* out = zz == 0 ? O0 : zz == 1 ? O1 : zz == 2 ? O2 : O3;
  const float scale = zz == 0 ? QSCALE : 1.0f;
  const int n0 = blockIdx.x * 32, k0 = blockIdx.y * 32;
#pragma unroll
  for (int i = 0; i < 4; ++i)
    tile[ty + i * 8][tx] = in[(size_t)(k0 + ty + i * 8) * DMODEL + n0 + tx];
  __syncthreads();
#pragma unroll
  for (int i = 0; i < 4; ++i)
    out[(size_t)(n0 + ty + i * 8) * DMODEL + k0 + tx] =
        f2bf(tile[tx][ty + i * 8] * scale);
}

// ---------------------------------------------------------------------------
// Fused Q/K/V projection GEMM, global_load_lds(16B) staging, XOR-swizzled on
// the GLOBAL side. 128x128 tile, BK=64, 4 waves. Epilogues scatter to the
// fragment-major layouts consumed by flash_mfma.
// ---------------------------------------------------------------------------
__global__ __launch_bounds__(256) void mfma_gemm_qkv(
    const ushort* __restrict__ pb, const ushort* __restrict__ xb,
    const ushort* __restrict__ wqt, const ushort* __restrict__ wkt,
    const ushort* __restrict__ wvt, ushort* __restrict__ qws,
    ushort* __restrict__ kws, ushort* __restrict__ vws) {
  __shared__ __align__(16) ushort As[128 * 64];
  __shared__ __align__(16) ushort Bs[128 * 64];
  const int z = blockIdx.z;
  const ushort* A = (z == 0) ? pb : xb;
  const ushort* Bt = (z == 0) ? wqt : (z == 1) ? wkt : wvt;

  const int t = threadIdx.x;
  const int w = t >> 6, lane = t & 63, ln = lane & 15, q = lane >> 4;
  const int wm = w & 1, wn = w >> 1;
  const int row0 = blockIdx.y * 128, col0 = blockIdx.x * 128;
  const int sw = ln & 7;

  f32x4 acc[4][4];
#pragma unroll
  for (int i = 0; i < 4; ++i)
#pragma unroll
    for (int j = 0; j < 4; ++j) acc[i][j] = (f32x4){0.f, 0.f, 0.f, 0.f};

  for (int k0 = 0; k0 < DMODEL; k0 += 64) {
    __syncthreads();  // prior frag reads done
#pragma unroll
    for (int rep = 0; rep < 4; ++rep) {
      const int u0 = rep * 256 + w * 64;
      const int u = u0 + lane;
      const int r = u >> 3, gl = (u & 7) ^ (r & 7);
      gld16(&A[(size_t)(row0 + r) * DMODEL + k0 + gl * 8], &As[u0 * 8]);
      gld16(&Bt[(size_t)(col0 + r) * DMODEL + k0 + gl * 8], &Bs[u0 * 8]);
    }
    __syncthreads();  // vmcnt drain
#pragma unroll
    for (int ks = 0; ks < 2; ++ks) {
      short8 af[4], bf[4];
#pragma unroll
      for (int rt = 0; rt < 4; ++rt)
        af[rt] = *(const short8*)&As[(wm * 64 + rt * 16 + ln) * 64 +
                                     (((ks * 4 + q) ^ sw) * 8)];
#pragma unroll
      for (int ct = 0; ct < 4; ++ct)
        bf[ct] = *(const short8*)&Bs[(wn * 64 + ct * 16 + ln) * 64 +
                                     (((ks * 4 + q) ^ sw) * 8)];
#pragma unroll
      for (int rt = 0; rt < 4; ++rt)
#pragma unroll
        for (int ct = 0; ct < 4; ++ct)
          acc[rt][ct] = __builtin_amdgcn_mfma_f32_16x16x32_bf16(af[rt], bf[ct],
                                                                acc[rt][ct], 0, 0, 0);
    }
  }

  if (z < 2) {
    ushort* dst = z == 0 ? qws : kws;
#pragma unroll
    for (int rt = 0; rt < 4; ++rt)
#pragma unroll
      for (int ct = 0; ct < 4; ++ct) {
        const int c = col0 + wn * 64 + ct * 16 + ln;
        const int h = c >> 6, d = c & 63;
#pragma unroll
        for (int reg = 0; reg < 4; ++reg) {
          const int r = row0 + wm * 64 + rt * 16 + q * 4 + reg;
          const int b = r >> 11, s = r & (SEQ - 1);
          dst[qk_idx(b * HEADS + h, s, d)] = f2bf(acc[rt][ct][reg]);
        }
      }
  } else {
#pragma unroll
    for (int rt = 0; rt < 4; ++rt)
#pragma unroll
      for (int ct = 0; ct < 4; ++ct) {
        const int c = col0 + wn * 64 + ct * 16 + ln;
        const int h = c >> 6, d = c & 63;
        const int r0 = row0 + wm * 64 + rt * 16 + q * 4;
        const int b = r0 >> 11, s0 = r0 & (SEQ - 1);
        ushort4 u4 = make_ushort4(f2bf(acc[rt][ct][0]), f2bf(acc[rt][ct][1]),
                                  f2bf(acc[rt][ct][2]), f2bf(acc[rt][ct][3]));
        *(ushort4*)&vws[v_idx(b * HEADS + h, s0, d)] = u4;
      }
  }
}

// ---------------------------------------------------------------------------
// Flash attention v3: wave = 32 Q rows (2x16 register blocking), K/V staged
// once per block-iter via global_load_lds (shared by all 4 waves), m97-style
// 2-barrier K-loop. K-split x2 into disjoint partial buffers (max-free exp2
// softmax => partials additive). Grid (16 qt, 32 bh, 2 seg) = 1024 blocks
// = 4 blocks/CU = 16 waves/CU. LDS 35 KB/block.
// ---------------------------------------------------------------------------
__global__ __launch_bounds__(256, 4) void flash_mfma(
    const ushort* __restrict__ Qg, const ushort* __restrict__ Kg,
    const ushort* __restrict__ Vg, float* __restrict__ PO0,
    float* __restrict__ PO1, float* __restrict__ L0, float* __restrict__ L1) {
  __shared__ __align__(16) ushort Kst[8 * 512];   // 8 frags x 1 KB
  __shared__ __align__(16) ushort Vst[8 * 512];   // 8 frags x 1 KB
  __shared__ __align__(16) ushort Ps[128 * 72];   // P tile, wave-private rows

  const int t = threadIdx.x;
  const int w = t >> 6, lane = t & 63, ln = lane & 15, q = lane >> 4;
  const int qt = blockIdx.x;   // 0..15 (128-row Q tile)
  const int bh = blockIdx.y;   // 0..31
  const int seg = blockIdx.z;  // 0..1

  float* __restrict__ PO = seg ? PO1 : PO0;
  float* __restrict__ Lb = seg ? L1 : L0;

  const ushort* qg = Qg + (size_t)bh * SEQ * DH;
  const ushort* kg = Kg + (size_t)bh * SEQ * DH;
  const ushort* vg = Vg + (size_t)bh * DH * SEQ;

  // Q A-fragments (2 row-tiles x 2 k-halves), coalesced lane*16B loads
  short8 qf[2][2];
#pragma unroll
  for (int rt = 0; rt < 2; ++rt)
#pragma unroll
    for (int ks = 0; ks < 2; ++ks)
      qf[rt][ks] = *(const short8*)
          &qg[(((size_t)(qt * 8 + w * 2 + rt) * 2 + ks) * 64 + lane) * 8];

  float l_i[2][4];
  f32x4 acc_o[2][4];
#pragma unroll
  for (int rt = 0; rt < 2; ++rt)
#pragma unroll
    for (int reg = 0; reg < 4; ++reg) l_i[rt][reg] = 0.f;
#pragma unroll
  for (int rt = 0; rt < 2; ++rt)
#pragma unroll
    for (int nt = 0; nt < 4; ++nt) acc_o[rt][nt] = (f32x4){0.f, 0.f, 0.f, 0.f};

  for (int kt = seg * 16; kt < seg * 16 + 16; ++kt) {
    __syncthreads();  // all waves done reading prev iter's Kst/Vst
    // stage this iter's 16 frags (16 KB); wave w issues 4 DMAs
#pragma unroll
    for (int i = 0; i < 4; ++i) {
      const int f = w * 4 + i;  // wave-uniform
      if (f < 8) {
        gld16(&kg[((size_t)(kt * 8 + f)) * 512 + lane * 8], &Kst[f * 512]);
      } else {
        const int f2 = f - 8, nt = f2 >> 1, ks2 = f2 & 1;
        gld16(&vg[((size_t)(nt * (SEQ / 32) + kt * 2 + ks2)) * 512 + lane * 8],
              &Vst[f2 * 512]);
      }
    }
    __syncthreads();  // vmcnt drain: staging visible

    // S = Q @ K^T (wave: 32 x 64); each K B-frag feeds 2 row-tiles
    f32x4 accs[2][4];
#pragma unroll
    for (int rt = 0; rt < 2; ++rt)
#pragma unroll
      for (int ct = 0; ct < 4; ++ct) accs[rt][ct] = (f32x4){0.f, 0.f, 0.f, 0.f};
#pragma unroll
    for (int ks = 0; ks < 2; ++ks)
#pragma unroll
      for (int ct = 0; ct < 4; ++ct) {
        const short8 bf = *(const short8*)&Kst[(ct * 2 + ks) * 512 + lane * 8];
#pragma unroll
        for (int rt = 0; rt < 2; ++rt)
          accs[rt][ct] = __builtin_amdgcn_mfma_f32_16x16x32_bf16(
              qf[rt][ks], bf, accs[rt][ct], 0, 0, 0);
      }

    // p = 2^s (Q pre-scaled), lane-partial l, P -> wave-private LDS rows
    // cheap round-half-up bf16: (u + 0x8000) >> 16 (p > 0 always)
#pragma unroll
    for (int rt = 0; rt < 2; ++rt)
#pragma unroll
      for (int ct = 0; ct < 4; ++ct)
#pragma unroll
        for (int reg = 0; reg < 4; ++reg) {
          const float p = __builtin_amdgcn_exp2f(accs[rt][ct][reg]);
          l_i[rt][reg] += p;
          union { float f; unsigned u; } v; v.f = p;
          Ps[(w * 32 + rt * 16 + q * 4 + reg) * 72 + ct * 16 + ln] =
              (ushort)((v.u + 0x8000u) >> 16);
        }

    // O += P @ V; each V B-frag feeds 2 row-tiles
#pragma unroll
    for (int ks2 = 0; ks2 < 2; ++ks2) {
      short8 pa[2];
#pragma unroll
      for (int rt = 0; rt < 2; ++rt)
        pa[rt] = *(const short8*)&Ps[(w * 32 + rt * 16 + ln) * 72 +
                                     ks2 * 32 + q * 8];
#pragma unroll
      for (int nt = 0; nt < 4; ++nt) {
        const short8 bv = *(const short8*)&Vst[(nt * 2 + ks2) * 512 + lane * 8];
#pragma unroll
        for (int rt = 0; rt < 2; ++rt)
          acc_o[rt][nt] = __builtin_amdgcn_mfma_f32_16x16x32_bf16(
              pa[rt], bv, acc_o[rt][nt], 0, 0, 0);
      }
    }
  }

  // epilogue: write RAW partials (no normalize) to this segment's buffers
#pragma unroll
  for (int rt = 0; rt < 2; ++rt)
#pragma unroll
    for (int reg = 0; reg < 4; ++reg) {
      float l = l_i[rt][reg];
      l += __shfl_xor(l, 1, 16);
      l += __shfl_xor(l, 2, 16);
      l += __shfl_xor(l, 4, 16);
      l += __shfl_xor(l, 8, 16);
      const int s = qt * 128 + w * 32 + rt * 16 + q * 4 + reg;
      if (ln == 0) Lb[bh * SEQ + s] = l;
#pragma unroll
      for (int nt = 0; nt < 4; ++nt)
        PO[((size_t)bh * SEQ + s) * DH + nt * 16 + ln] = acc_o[rt][nt][reg];
    }
}

// ---------------------------------------------------------------------------
// merge partials: aws = bf16( (PO0+PO1) / (L0+L1) ), layout [b*2048+s][h*64+d]
// ---------------------------------------------------------------------------
__global__ __launch_bounds__(256) void merge_reduce(
    const float4* __restrict__ PO0, const float4* __restrict__ PO1,
    const float* __restrict__ L0, const float* __restrict__ L1,
    ushort* __restrict__ aws) {
  const int i = blockIdx.x * 256 + threadIdx.x;  // float4 units, 0..1M-1
  const int row = i >> 4, d4 = i & 15;
  const int bh = row >> 11, s = row & (SEQ - 1);
  const int b = bh >> 4, h = bh & 15;
  const float4 a = PO0[i];
  const float4 c = PO1[i];
  const float inv = 1.0f / (L0[row] + L1[row]);
  ushort4 u = make_ushort4(f2bf((a.x + c.x) * inv), f2bf((a.y + c.y) * inv),
                           f2bf((a.z + c.z) * inv), f2bf((a.w + c.w) * inv));
  *(ushort4*)&aws[((size_t)b * SEQ + s) * DMODEL + h * DH + d4 * 4] = u;
}

// ---------------------------------------------------------------------------
// Output projection: out = aws[4096,1024] @ WoT^T + bo (fp32). 64x128 tile,
// BK=64, global_load_lds staging, 512 blocks.
// ---------------------------------------------------------------------------
__global__ __launch_bounds__(256) void mfma_gemm_out(const ushort* __restrict__ A,
                                                     const ushort* __restrict__ Bt,
                                                     const float* __restrict__ bias,
                                                     float* __restrict__ dst) {
  __shared__ __align__(16) ushort As[64 * 64];
  __shared__ __align__(16) ushort Bs[128 * 64];
  const int t = threadIdx.x;
  const int w = t >> 6, lane = t & 63, ln = lane & 15, q = lane >> 4;
  const int wm = w & 1, wn = w >> 1;
  const int row0 = blockIdx.y * 64, col0 = blockIdx.x * 128;
  const int sw = ln & 7;

  f32x4 acc[2][4];
#pragma unroll
  for (int i = 0; i < 2; ++i)
#pragma unroll
    for (int j = 0; j < 4; ++j) acc[i][j] = (f32x4){0.f, 0.f, 0.f, 0.f};

  for (int k0 = 0; k0 < DMODEL; k0 += 64) {
    __syncthreads();
#pragma unroll
    for (int rep = 0; rep < 2; ++rep) {
      const int u0 = rep * 256 + w * 64;
      const int u = u0 + lane;
      const int r = u >> 3, gl = (u & 7) ^ (r & 7);
      gld16(&A[(size_t)(row0 + r) * DMODEL + k0 + gl * 8], &As[u0 * 8]);
    }
#pragma unroll
    for (int rep = 0; rep < 4; ++rep) {
      const int u0 = rep * 256 + w * 64;
      const int u = u0 + lane;
      const int r = u >> 3, gl = (u & 7) ^ (r & 7);
      gld16(&Bt[(size_t)(col0 + r) * DMODEL + k0 + gl * 8], &Bs[u0 * 8]);
    }
    __syncthreads();
#pragma unroll
    for (int ks = 0; ks < 2; ++ks) {
      short8 af[2], bf[4];
#pragma unroll
      for (int rt = 0; rt < 2; ++rt)
        af[rt] = *(const short8*)&As[(wm * 32 + rt * 16 + ln) * 64 +
                                     (((ks * 4 + q) ^ sw) * 8)];
#pragma unroll
      for (int ct = 0; ct < 4; ++ct)
        bf[ct] = *(const short8*)&Bs[(wn * 64 + ct * 16 + ln) * 64 +
                                     (((ks * 4 + q) ^ sw) * 8)];
#pragma unroll
      for (int rt = 0; rt < 2; ++rt)
#pragma unroll
        for (int ct = 0; ct < 4; ++ct)
          acc[rt][ct] = __builtin_amdgcn_mfma_f32_16x16x32_bf16(af[rt], bf[ct],
                                                                acc[rt][ct], 0, 0, 0);
    }
  }

#pragma unroll
  for (int rt = 0; rt < 2; ++rt)
#pragma unroll
    for (int ct = 0; ct < 4; ++ct) {
      const int c = col0 + wn * 64 + ct * 16 + ln;
      const float bi = bias[c];
#pragma unroll
      for (int reg = 0; reg < 4; ++reg) {
        const int r = row0 + wm * 32 + rt * 16 + q * 4 + reg;
        dst[(size_t)r * DMODEL + c] = acc[rt][ct][reg] + bi;
      }
    }
}

extern "C" void kernel_launch(void* const* d_in, const int* in_sizes, int n_in,
                              void* d_out, int out_size, void* d_ws,
                              size_t ws_size, hipStream_t stream) {
  const float* patch = (const float*)d_in[0];
  const float* pixel = (const float*)d_in[1];
  const float* Wq = (const float*)d_in[2];
  const float* Wk = (const float*)d_in[3];
  const float* Wv = (const float*)d_in[4];
  const float* Wo = (const float*)d_in[5];
  const float* bo = (const float*)d_in[6];
  float* out = (float*)d_out;

  const size_t E = (size_t)2 * SEQ * DMODEL;  // 4,194,304
  const size_t W = (size_t)DMODEL * DMODEL;   // 1,048,576
  ushort* pb  = (ushort*)d_ws;      // patch bf16   (dead after qkv -> PO0)
  ushort* xb  = pb + E;             // pixel bf16   (part of PO0)
  ushort* wqt = xb + E;             // Wq^T*QSCALE  (dead after qkv -> L0/L1)
  ushort* wkt = wqt + W;
  ushort* wvt = wkt + W;
  ushort* wot = wvt + W;            // live until mfma_gemm_out
  ushort* qws = wot + W;            // Q fragment-major
  ushort* kws = qws + E;            // K fragment-major
  ushort* vws = kws + E;            // V^T fragment-major
  ushort* aws = vws + E;            // [4096][1024] row-major bf16

  // Partial buffers (no extra ws): PO0 overlays pb+xb (dead after qkv);
  // PO1 = d_out itself (16 MB fp32, fully rewritten by final GEMM);
  // L0/L1 overlay wqt (dead after qkv).
  float* PO0 = (float*)pb;
  float* PO1 = out;
  float* L0 = (float*)wqt;
  float* L1 = L0 + 32 * SEQ;

  prologue<<<dim3(32, 32, 6), dim3(32, 8), 0, stream>>>(
      patch, pixel, Wq, Wk, Wv, Wo, pb, xb, wqt, wkt, wvt, wot);
  mfma_gemm_qkv<<<dim3(8, 32, 3), 256, 0, stream>>>(pb, xb, wqt, wkt, wvt,
                                                    qws, kws, vws);
  flash_mfma<<<dim3(16, 32, 2), 256, 0, stream>>>(qws, kws, vws, PO0, PO1, L0, L1);
  merge_reduce<<<dim3((32 * SEQ * DH / 4) / 256), 256, 0, stream>>>(
      (const float4*)PO0, (const float4*)PO1, L0, L1, aws);
  mfma_gemm_out<<<dim3(8, 64), 256, 0, stream>>>(aws, wot, bo, out);
}

// Round 8
// 195.891 us; speedup vs baseline: 1.1544x; 1.0607x over previous
//
#include <hip/hip_runtime.h>

#define SEQ 2048
#define DMODEL 1024
#define HEADS 16
#define DH 64
// fold (1/sqrt(64)) * log2(e) into Wq so scores arrive in exp2 domain
#define QSCALE 0.180336880f

typedef __attribute__((ext_vector_type(8))) short short8;
typedef __attribute__((ext_vector_type(4))) float f32x4;

__device__ __forceinline__ ushort f2bf(float x) {
  union { float f; unsigned u; } v; v.f = x;
  return (ushort)((v.u + 0x7fffu + ((v.u >> 16) & 1u)) >> 16);
}

// async global->LDS, 16B per lane. LDS dest = wave-uniform base + lane*16.
__device__ __forceinline__ void gld16(const ushort* g, ushort* l) {
  __builtin_amdgcn_global_load_lds(
      (const __attribute__((address_space(1))) unsigned int*)g,
      (__attribute__((address_space(3))) unsigned int*)l, 16, 0, 0);
}

// fragment-major index for Q/K [bh][s>>4][d>>5][lane q*16+ln][j=d&7]
__device__ __forceinline__ size_t qk_idx(int bh, int s, int d) {
  return ((((size_t)bh * (SEQ / 16) + (s >> 4)) * 2 + (d >> 5)) * 64 +
          ((d >> 3) & 3) * 16 + (s & 15)) * 8 + (d & 7);
}
// fragment-major index for V^T [bh][d>>4][s>>5][lane][j=s&7]
__device__ __forceinline__ size_t v_idx(int bh, int s, int d) {
  return ((((size_t)bh * 4 + (d >> 4)) * (SEQ / 32) + (s >> 5)) * 64 +
          ((s >> 3) & 3) * 16 + (d & 15)) * 8 + (s & 7);
}

// ---------------------------------------------------------------------------
// Fused prologue. z=0/1: fp32->bf16 cast of patch/pixel (4x float4/thread).
// z=2..5: transpose-cast Wq*QSCALE / Wk / Wv / Wo to [N][K] bf16.
// ---------------------------------------------------------------------------
__global__ __launch_bounds__(256) void prologue(
    const float* __restrict__ patch, const float* __restrict__ pixel,
    const float* __restrict__ W0, const float* __restrict__ W1,
    const float* __restrict__ W2, const float* __restrict__ W3,
    ushort* __restrict__ pb, ushort* __restrict__ xb,
    ushort* __restrict__ O0, ushort* __restrict__ O1,
    ushort* __restrict__ O2, ushort* __restrict__ O3) {
  const int z = blockIdx.z;
  const int tx = threadIdx.x, ty = threadIdx.y;
  if (z < 2) {
    const float4* in = (const float4*)(z ? pixel : patch);
    ushort4* out = (ushort4*)(z ? xb : pb);
    const int base = (blockIdx.y * 32 + blockIdx.x) * 256 + ty * 32 + tx;
#pragma unroll
    for (int rep = 0; rep < 4; ++rep) {
      const int i = base + rep * 262144;
      float4 f = in[i];
      out[i] = make_ushort4(f2bf(f.x), f2bf(f.y), f2bf(f.z), f2bf(f.w));
    }
    return;
  }
  __shared__ float tile[32][33];
  const int zz = z - 2;
  const float* in = zz == 0 ? W0 : zz == 1 ? W1 : zz == 2 ? W2 : W3;
  ushort* out = zz == 0 ? O0 : zz == 1 ? O1 : zz == 2 ? O2 : O3;
  const float scale = zz == 0 ? QSCALE : 1.0f;
  const int n0 = blockIdx.x * 32, k0 = blockIdx.y * 32;
#pragma unroll
  for (int i = 0; i < 4; ++i)
    tile[ty + i * 8][tx] = in[(size_t)(k0 + ty + i * 8) * DMODEL + n0 + tx];
  __syncthreads();
#pragma unroll
  for (int i = 0; i < 4; ++i)
    out[(size_t)(n0 + ty + i * 8) * DMODEL + k0 + tx] =
        f2bf(tile[tx][ty + i * 8] * scale);
}

// ---------------------------------------------------------------------------
// Fused Q/K/V projection GEMM, global_load_lds(16B) staging, XOR-swizzled on
// the GLOBAL side. 128x128 tile, BK=64, 4 waves. Epilogues scatter to the
// fragment-major layouts consumed by flash_mfma.
// ---------------------------------------------------------------------------
__global__ __launch_bounds__(256) void mfma_gemm_qkv(
    const ushort* __restrict__ pb, const ushort* __restrict__ xb,
    const ushort* __restrict__ wqt, const ushort* __restrict__ wkt,
    const ushort* __restrict__ wvt, ushort* __restrict__ qws,
    ushort* __restrict__ kws, ushort* __restrict__ vws) {
  __shared__ __align__(16) ushort As[128 * 64];
  __shared__ __align__(16) ushort Bs[128 * 64];
  const int z = blockIdx.z;
  const ushort* A = (z == 0) ? pb : xb;
  const ushort* Bt = (z == 0) ? wqt : (z == 1) ? wkt : wvt;

  const int t = threadIdx.x;
  const int w = t >> 6, lane = t & 63, ln = lane & 15, q = lane >> 4;
  const int wm = w & 1, wn = w >> 1;
  const int row0 = blockIdx.y * 128, col0 = blockIdx.x * 128;
  const int sw = ln & 7;

  f32x4 acc[4][4];
#pragma unroll
  for (int i = 0; i < 4; ++i)
#pragma unroll
    for (int j = 0; j < 4; ++j) acc[i][j] = (f32x4){0.f, 0.f, 0.f, 0.f};

  for (int k0 = 0; k0 < DMODEL; k0 += 64) {
    __syncthreads();  // prior frag reads done
#pragma unroll
    for (int rep = 0; rep < 4; ++rep) {
      const int u0 = rep * 256 + w * 64;
      const int u = u0 + lane;
      const int r = u >> 3, gl = (u & 7) ^ (r & 7);
      gld16(&A[(size_t)(row0 + r) * DMODEL + k0 + gl * 8], &As[u0 * 8]);
      gld16(&Bt[(size_t)(col0 + r) * DMODEL + k0 + gl * 8], &Bs[u0 * 8]);
    }
    __syncthreads();  // vmcnt drain
#pragma unroll
    for (int ks = 0; ks < 2; ++ks) {
      short8 af[4], bf[4];
#pragma unroll
      for (int rt = 0; rt < 4; ++rt)
        af[rt] = *(const short8*)&As[(wm * 64 + rt * 16 + ln) * 64 +
                                     (((ks * 4 + q) ^ sw) * 8)];
#pragma unroll
      for (int ct = 0; ct < 4; ++ct)
        bf[ct] = *(const short8*)&Bs[(wn * 64 + ct * 16 + ln) * 64 +
                                     (((ks * 4 + q) ^ sw) * 8)];
#pragma unroll
      for (int rt = 0; rt < 4; ++rt)
#pragma unroll
        for (int ct = 0; ct < 4; ++ct)
          acc[rt][ct] = __builtin_amdgcn_mfma_f32_16x16x32_bf16(af[rt], bf[ct],
                                                                acc[rt][ct], 0, 0, 0);
    }
  }

  if (z < 2) {
    ushort* dst = z == 0 ? qws : kws;
#pragma unroll
    for (int rt = 0; rt < 4; ++rt)
#pragma unroll
      for (int ct = 0; ct < 4; ++ct) {
        const int c = col0 + wn * 64 + ct * 16 + ln;
        const int h = c >> 6, d = c & 63;
#pragma unroll
        for (int reg = 0; reg < 4; ++reg) {
          const int r = row0 + wm * 64 + rt * 16 + q * 4 + reg;
          const int b = r >> 11, s = r & (SEQ - 1);
          dst[qk_idx(b * HEADS + h, s, d)] = f2bf(acc[rt][ct][reg]);
        }
      }
  } else {
#pragma unroll
    for (int rt = 0; rt < 4; ++rt)
#pragma unroll
      for (int ct = 0; ct < 4; ++ct) {
        const int c = col0 + wn * 64 + ct * 16 + ln;
        const int h = c >> 6, d = c & 63;
        const int r0 = row0 + wm * 64 + rt * 16 + q * 4;
        const int b = r0 >> 11, s0 = r0 & (SEQ - 1);
        ushort4 u4 = make_ushort4(f2bf(acc[rt][ct][0]), f2bf(acc[rt][ct][1]),
                                  f2bf(acc[rt][ct][2]), f2bf(acc[rt][ct][3]));
        *(ushort4*)&vws[v_idx(b * HEADS + h, s0, d)] = u4;
      }
  }
}

// ---------------------------------------------------------------------------
// Flash attention v4: Q-tile 128 (4 waves, 32 rows/wave via 2x16 blocking),
// full 32-iter K sweep, DOUBLE-BUFFERED K/V staging with ONE barrier per
// iter (DMA for kt+1 issued before compute of kt -> vmcnt drain at the
// barrier is ~free). No K-split, no merge: normalize + write bf16 directly.
// Grid (x=bh 32, y=qt 16) = 512 blocks; x=bh pins each bh's 16 blocks to one
// XCD (id%8 = bh%8) so K/V stay in one L2. LDS 50 KB -> 3 blocks/CU.
// ---------------------------------------------------------------------------
__global__ __launch_bounds__(256, 3) void flash_mfma(
    const ushort* __restrict__ Qg, const ushort* __restrict__ Kg,
    const ushort* __restrict__ Vg, ushort* __restrict__ Og) {
  __shared__ __align__(16) ushort Kst[2][8 * 512];  // 2 x 8 KB
  __shared__ __align__(16) ushort Vst[2][8 * 512];  // 2 x 8 KB
  __shared__ __align__(16) ushort Ps[128 * 72];     // 18 KB, wave-private rows

  const int t = threadIdx.x;
  const int w = t >> 6, lane = t & 63, ln = lane & 15, q = lane >> 4;
  const int bh = blockIdx.x;   // 0..31  (XCD-pinning: id%8 = bh%8)
  const int qt = blockIdx.y;   // 0..15  (128-row Q tile)

  const ushort* qg = Qg + (size_t)bh * SEQ * DH;
  const ushort* kg = Kg + (size_t)bh * SEQ * DH;
  const ushort* vg = Vg + (size_t)bh * DH * SEQ;

  // Q A-fragments (2 row-tiles x 2 k-halves), coalesced lane*16B loads
  short8 qf[2][2];
#pragma unroll
  for (int rt = 0; rt < 2; ++rt)
#pragma unroll
    for (int ks = 0; ks < 2; ++ks)
      qf[rt][ks] = *(const short8*)
          &qg[(((size_t)(qt * 8 + w * 2 + rt) * 2 + ks) * 64 + lane) * 8];

  float l_i[2][4];
  f32x4 acc_o[2][4];
#pragma unroll
  for (int rt = 0; rt < 2; ++rt)
#pragma unroll
    for (int reg = 0; reg < 4; ++reg) l_i[rt][reg] = 0.f;
#pragma unroll
  for (int rt = 0; rt < 2; ++rt)
#pragma unroll
    for (int nt = 0; nt < 4; ++nt) acc_o[rt][nt] = (f32x4){0.f, 0.f, 0.f, 0.f};

  // stage kt=0 into buffer 0 (wave w issues frags w*4..w*4+3)
#pragma unroll
  for (int i = 0; i < 4; ++i) {
    const int f = w * 4 + i;
    if (f < 8) {
      gld16(&kg[(size_t)(0 * 8 + f) * 512 + lane * 8], &Kst[0][f * 512]);
    } else {
      const int f2 = f - 8, nt = f2 >> 1, ks2 = f2 & 1;
      gld16(&vg[(size_t)(nt * (SEQ / 32) + 0 * 2 + ks2) * 512 + lane * 8],
            &Vst[0][f2 * 512]);
    }
  }
  __syncthreads();  // drain prologue DMA

  for (int kt = 0; kt < SEQ / 64; ++kt) {
    const int cur = kt & 1;
    // issue NEXT iter's DMA first (lands during this iter's compute)
    if (kt + 1 < SEQ / 64) {
      const int nxt = cur ^ 1;
#pragma unroll
      for (int i = 0; i < 4; ++i) {
        const int f = w * 4 + i;
        if (f < 8) {
          gld16(&kg[(size_t)((kt + 1) * 8 + f) * 512 + lane * 8],
                &Kst[nxt][f * 512]);
        } else {
          const int f2 = f - 8, nt = f2 >> 1, ks2 = f2 & 1;
          gld16(&vg[(size_t)(nt * (SEQ / 32) + (kt + 1) * 2 + ks2) * 512 +
                    lane * 8],
                &Vst[nxt][f2 * 512]);
        }
      }
    }

    // S = Q @ K^T (wave: 32 x 64); each K B-frag feeds 2 row-tiles
    f32x4 accs[2][4];
#pragma unroll
    for (int rt = 0; rt < 2; ++rt)
#pragma unroll
      for (int ct = 0; ct < 4; ++ct) accs[rt][ct] = (f32x4){0.f, 0.f, 0.f, 0.f};
#pragma unroll
    for (int ks = 0; ks < 2; ++ks)
#pragma unroll
      for (int ct = 0; ct < 4; ++ct) {
        const short8 bf = *(const short8*)&Kst[cur][(ct * 2 + ks) * 512 + lane * 8];
#pragma unroll
        for (int rt = 0; rt < 2; ++rt)
          accs[rt][ct] = __builtin_amdgcn_mfma_f32_16x16x32_bf16(
              qf[rt][ks], bf, accs[rt][ct], 0, 0, 0);
      }

    // p = 2^s (Q pre-scaled), lane-partial l, P -> wave-private LDS rows
#pragma unroll
    for (int rt = 0; rt < 2; ++rt)
#pragma unroll
      for (int ct = 0; ct < 4; ++ct)
#pragma unroll
        for (int reg = 0; reg < 4; ++reg) {
          const float p = __builtin_amdgcn_exp2f(accs[rt][ct][reg]);
          l_i[rt][reg] += p;
          union { float f; unsigned u; } v; v.f = p;
          Ps[(w * 32 + rt * 16 + q * 4 + reg) * 72 + ct * 16 + ln] =
              (ushort)((v.u + 0x8000u) >> 16);
        }

    // O += P @ V; each V B-frag feeds 2 row-tiles
#pragma unroll
    for (int ks2 = 0; ks2 < 2; ++ks2) {
      short8 pa[2];
#pragma unroll
      for (int rt = 0; rt < 2; ++rt)
        pa[rt] = *(const short8*)&Ps[(w * 32 + rt * 16 + ln) * 72 +
                                     ks2 * 32 + q * 8];
#pragma unroll
      for (int nt = 0; nt < 4; ++nt) {
        const short8 bv = *(const short8*)&Vst[cur][(nt * 2 + ks2) * 512 + lane * 8];
#pragma unroll
        for (int rt = 0; rt < 2; ++rt)
          acc_o[rt][nt] = __builtin_amdgcn_mfma_f32_16x16x32_bf16(
              pa[rt], bv, acc_o[rt][nt], 0, 0, 0);
      }
    }

    __syncthreads();  // single barrier: next DMA drained + buffers swappable
  }

  // epilogue: reduce l over the quad's 16 lanes, normalize, write aws bf16
  const int b = bh >> 4, h = bh & 15;
#pragma unroll
  for (int rt = 0; rt < 2; ++rt)
#pragma unroll
    for (int reg = 0; reg < 4; ++reg) {
      float l = l_i[rt][reg];
      l += __shfl_xor(l, 1, 16);
      l += __shfl_xor(l, 2, 16);
      l += __shfl_xor(l, 4, 16);
      l += __shfl_xor(l, 8, 16);
      const float inv = 1.0f / l;
      const int s = qt * 128 + w * 32 + rt * 16 + q * 4 + reg;
#pragma unroll
      for (int nt = 0; nt < 4; ++nt)
        Og[(size_t)(b * SEQ + s) * DMODEL + h * DH + nt * 16 + ln] =
            f2bf(acc_o[rt][nt][reg] * inv);
    }
}

// ---------------------------------------------------------------------------
// Output projection: out = aws[4096,1024] @ WoT^T + bo (fp32). 64x128 tile,
// BK=64, global_load_lds staging, 512 blocks.
// ---------------------------------------------------------------------------
__global__ __launch_bounds__(256) void mfma_gemm_out(const ushort* __restrict__ A,
                                                     const ushort* __restrict__ Bt,
                                                     const float* __restrict__ bias,
                                                     float* __restrict__ dst) {
  __shared__ __align__(16) ushort As[64 * 64];
  __shared__ __align__(16) ushort Bs[128 * 64];
  const int t = threadIdx.x;
  const int w = t >> 6, lane = t & 63, ln = lane & 15, q = lane >> 4;
  const int wm = w & 1, wn = w >> 1;
  const int row0 = blockIdx.y * 64, col0 = blockIdx.x * 128;
  const int sw = ln & 7;

  f32x4 acc[2][4];
#pragma unroll
  for (int i = 0; i < 2; ++i)
#pragma unroll
    for (int j = 0; j < 4; ++j) acc[i][j] = (f32x4){0.f, 0.f, 0.f, 0.f};

  for (int k0 = 0; k0 < DMODEL; k0 += 64) {
    __syncthreads();
#pragma unroll
    for (int rep = 0; rep < 2; ++rep) {
      const int u0 = rep * 256 + w * 64;
      const int u = u0 + lane;
      const int r = u >> 3, gl = (u & 7) ^ (r & 7);
      gld16(&A[(size_t)(row0 + r) * DMODEL + k0 + gl * 8], &As[u0 * 8]);
    }
#pragma unroll
    for (int rep = 0; rep < 4; ++rep) {
      const int u0 = rep * 256 + w * 64;
      const int u = u0 + lane;
      const int r = u >> 3, gl = (u & 7) ^ (r & 7);
      gld16(&Bt[(size_t)(col0 + r) * DMODEL + k0 + gl * 8], &Bs[u0 * 8]);
    }
    __syncthreads();
#pragma unroll
    for (int ks = 0; ks < 2; ++ks) {
      short8 af[2], bf[4];
#pragma unroll
      for (int rt = 0; rt < 2; ++rt)
        af[rt] = *(const short8*)&As[(wm * 32 + rt * 16 + ln) * 64 +
                                     (((ks * 4 + q) ^ sw) * 8)];
#pragma unroll
      for (int ct = 0; ct < 4; ++ct)
        bf[ct] = *(const short8*)&Bs[(wn * 64 + ct * 16 + ln) * 64 +
                                     (((ks * 4 + q) ^ sw) * 8)];
#pragma unroll
      for (int rt = 0; rt < 2; ++rt)
#pragma unroll
        for (int ct = 0; ct < 4; ++ct)
          acc[rt][ct] = __builtin_amdgcn_mfma_f32_16x16x32_bf16(af[rt], bf[ct],
                                                                acc[rt][ct], 0, 0, 0);
    }
  }

#pragma unroll
  for (int rt = 0; rt < 2; ++rt)
#pragma unroll
    for (int ct = 0; ct < 4; ++ct) {
      const int c = col0 + wn * 64 + ct * 16 + ln;
      const float bi = bias[c];
#pragma unroll
      for (int reg = 0; reg < 4; ++reg) {
        const int r = row0 + wm * 32 + rt * 16 + q * 4 + reg;
        dst[(size_t)r * DMODEL + c] = acc[rt][ct][reg] + bi;
      }
    }
}

extern "C" void kernel_launch(void* const* d_in, const int* in_sizes, int n_in,
                              void* d_out, int out_size, void* d_ws,
                              size_t ws_size, hipStream_t stream) {
  const float* patch = (const float*)d_in[0];
  const float* pixel = (const float*)d_in[1];
  const float* Wq = (const float*)d_in[2];
  const float* Wk = (const float*)d_in[3];
  const float* Wv = (const float*)d_in[4];
  const float* Wo = (const float*)d_in[5];
  const float* bo = (const float*)d_in[6];
  float* out = (float*)d_out;

  const size_t E = (size_t)2 * SEQ * DMODEL;  // 4,194,304
  const size_t W = (size_t)DMODEL * DMODEL;   // 1,048,576
  ushort* pb  = (ushort*)d_ws;      // patch bf16
  ushort* xb  = pb + E;             // pixel bf16
  ushort* wqt = xb + E;             // Wq^T * QSCALE bf16 [N][K]
  ushort* wkt = wqt + W;
  ushort* wvt = wkt + W;
  ushort* wot = wvt + W;            // live until mfma_gemm_out
  ushort* qws = wot + W;            // Q fragment-major
  ushort* kws = qws + E;            // K fragment-major
  ushort* vws = kws + E;            // V^T fragment-major
  ushort* aws = vws + E;            // [4096][1024] row-major bf16

  prologue<<<dim3(32, 32, 6), dim3(32, 8), 0, stream>>>(
      patch, pixel, Wq, Wk, Wv, Wo, pb, xb, wqt, wkt, wvt, wot);
  mfma_gemm_qkv<<<dim3(8, 32, 3), 256, 0, stream>>>(pb, xb, wqt, wkt, wvt,
                                                    qws, kws, vws);
  flash_mfma<<<dim3(32, 16), 256, 0, stream>>>(qws, kws, vws, aws);
  mfma_gemm_out<<<dim3(8, 64), 256, 0, stream>>>(aws, wot, bo, out);
}